// Round 2
// baseline (518.303 us; speedup 1.0000x reference)
//
#include <hip/hip_runtime.h>
#include <hip/hip_fp16.h>

// Problem geometry: inputs (B=2, D=64, H=64, W=64, C=32) fp32, C innermost.
// Pass1: Sobel (VALID) -> mag = sqrt(gx^2+gy^2+gz^2) at 62^3 per (b,c)
// Pass2: Sobel on mag -> out = sqrt(gx^2+gy^2) + gz^2 at 60^3
// Result: mean(|out_pred - out_hr|) over 2*32*60^3 = 13,824,000 elems.
// Signs of gradients never matter (everything squared) -> conv-flip immaterial.
//
// R1: vectorize over C by 4 (C innermost): float4 global loads in pass1,
// uint2 (4 x fp16) loads in pass2. 4x fewer VMEM instructions + addr VALU.

constexpr int BDIM = 256;
constexpr size_t IN_B = 8388608;   // 64*64*64*32 elements per batch
constexpr int IN_D = 131072;       // 64*64*32
constexpr int IN_H = 2048;         // 64*32
constexpr int M = 62;              // mag spatial dim
constexpr int F = 60;              // final spatial dim
constexpr int C = 32;
constexpr int MROW = M * C;                      // 1984 elems per (z,y) mag row
constexpr size_t MAGSZ = (size_t)M * M * MROW;   // 7,626,496 halves per buffer
constexpr int P1_ITEMS = MROW / 4;               // 496 c4-groups per (z,y) row
constexpr int P2_ITEMS = F * C / 4;              // 480

union H4 { uint2 u; __half2 h[2]; };

// ---------------- Pass 1: input -> fp16 magnitude volume ----------------
__global__ __launch_bounds__(BDIM) void sobel_mag_kernel(
    const float* __restrict__ pred, const float* __restrict__ hr,
    __half* __restrict__ magP, __half* __restrict__ magH, int b)
{
    constexpr float S3[3] = {1.f, 2.f, 1.f};
    constexpr float D3[3] = {-1.f, 0.f, 1.f};
    const int z = blockIdx.x;   // [0,62)
    const int y = blockIdx.y;   // [0,62)
    const float* __restrict__ in  = blockIdx.z ? hr   : pred;
    __half*      __restrict__ mag = blockIdx.z ? magH : magP;

    const float* base = in + (size_t)b * IN_B + (size_t)z * IN_D + (size_t)y * IN_H;
    __half* mrow = mag + ((size_t)z * M + y) * MROW;

    for (int q = threadIdx.x; q < P1_ITEMS; q += BDIM) {
        // q indexes a group of 4 consecutive channels: elem idx = 4*q = x*32 + c
        float gx[4] = {0,0,0,0}, gy[4] = {0,0,0,0}, gz[4] = {0,0,0,0};
#pragma unroll
        for (int i = 0; i < 3; ++i) {
#pragma unroll
            for (int j = 0; j < 3; ++j) {
                const float4* p = reinterpret_cast<const float4*>(
                    base + 4 * q + i * IN_D + j * IN_H);
                float4 v0 = p[0];    // x
                float4 v1 = p[8];    // x+1  (+32 floats)
                float4 v2 = p[16];   // x+2  (+64 floats)
                const float cgx = D3[i] * S3[j];
                const float cgy = S3[i] * D3[j];
                const float cgz = S3[i] * S3[j];
                float v0a[4] = {v0.x, v0.y, v0.z, v0.w};
                float v1a[4] = {v1.x, v1.y, v1.z, v1.w};
                float v2a[4] = {v2.x, v2.y, v2.z, v2.w};
#pragma unroll
                for (int k = 0; k < 4; ++k) {
                    float sx = v0a[k] + 2.f * v1a[k] + v2a[k];
                    float dx = v2a[k] - v0a[k];
                    gx[k] += cgx * sx;
                    gy[k] += cgy * sx;
                    gz[k] += cgz * dx;
                }
            }
        }
        float m0 = sqrtf(gx[0]*gx[0] + gy[0]*gy[0] + gz[0]*gz[0]);
        float m1 = sqrtf(gx[1]*gx[1] + gy[1]*gy[1] + gz[1]*gz[1]);
        float m2 = sqrtf(gx[2]*gx[2] + gy[2]*gy[2] + gz[2]*gz[2]);
        float m3 = sqrtf(gx[3]*gx[3] + gy[3]*gy[3] + gz[3]*gz[3]);
        H4 o;
        o.h[0] = __floats2half2_rn(m0, m1);
        o.h[1] = __floats2half2_rn(m2, m3);
        *reinterpret_cast<uint2*>(mrow + 4 * q) = o.u;
    }
}

// ------- Pass 2: mag -> final, diff pred vs hr, per-block partial sum -------
__global__ __launch_bounds__(BDIM) void sobel2_diff_kernel(
    const __half* __restrict__ magP, const __half* __restrict__ magH,
    float* __restrict__ partial, int b)
{
    constexpr float S3[3] = {1.f, 2.f, 1.f};
    constexpr float D3[3] = {-1.f, 0.f, 1.f};
    const int z = blockIdx.x;   // [0,60)
    const int y = blockIdx.y;   // [0,60)

    float acc = 0.f;
    for (int q = threadIdx.x; q < P2_ITEMS; q += BDIM) {
        float gxP[4] = {0,0,0,0}, gyP[4] = {0,0,0,0}, gzP[4] = {0,0,0,0};
        float gxH[4] = {0,0,0,0}, gyH[4] = {0,0,0,0}, gzH[4] = {0,0,0,0};
#pragma unroll
        for (int i = 0; i < 3; ++i) {
#pragma unroll
            for (int j = 0; j < 3; ++j) {
                size_t off = ((size_t)(z + i) * M + (y + j)) * MROW + 4 * q;
                const uint2* pp = reinterpret_cast<const uint2*>(magP + off);
                const uint2* ph = reinterpret_cast<const uint2*>(magH + off);
                H4 P0, P1, P2, Hh0, Hh1, Hh2;
                P0.u = pp[0]; P1.u = pp[8]; P2.u = pp[16];   // +32/+64 halves
                Hh0.u = ph[0]; Hh1.u = ph[8]; Hh2.u = ph[16];
                const float cgx = D3[i] * S3[j];
                const float cgy = S3[i] * D3[j];
                const float cgz = S3[i] * S3[j];
                float2 p0l = __half22float2(P0.h[0]), p0h = __half22float2(P0.h[1]);
                float2 p1l = __half22float2(P1.h[0]), p1h = __half22float2(P1.h[1]);
                float2 p2l = __half22float2(P2.h[0]), p2h = __half22float2(P2.h[1]);
                float2 h0l = __half22float2(Hh0.h[0]), h0h = __half22float2(Hh0.h[1]);
                float2 h1l = __half22float2(Hh1.h[0]), h1h = __half22float2(Hh1.h[1]);
                float2 h2l = __half22float2(Hh2.h[0]), h2h = __half22float2(Hh2.h[1]);
                float p0a[4] = {p0l.x, p0l.y, p0h.x, p0h.y};
                float p1a[4] = {p1l.x, p1l.y, p1h.x, p1h.y};
                float p2a[4] = {p2l.x, p2l.y, p2h.x, p2h.y};
                float h0a[4] = {h0l.x, h0l.y, h0h.x, h0h.y};
                float h1a[4] = {h1l.x, h1l.y, h1h.x, h1h.y};
                float h2a[4] = {h2l.x, h2l.y, h2h.x, h2h.y};
#pragma unroll
                for (int k = 0; k < 4; ++k) {
                    float sxP = p0a[k] + 2.f * p1a[k] + p2a[k];
                    float dxP = p2a[k] - p0a[k];
                    float sxH = h0a[k] + 2.f * h1a[k] + h2a[k];
                    float dxH = h2a[k] - h0a[k];
                    gxP[k] += cgx * sxP;
                    gyP[k] += cgy * sxP;
                    gzP[k] += cgz * dxP;
                    gxH[k] += cgx * sxH;
                    gyH[k] += cgy * sxH;
                    gzH[k] += cgz * dxH;
                }
            }
        }
#pragma unroll
        for (int k = 0; k < 4; ++k) {
            float outP = sqrtf(gxP[k]*gxP[k] + gyP[k]*gyP[k]) + gzP[k]*gzP[k];
            float outH = sqrtf(gxH[k]*gxH[k] + gyH[k]*gyH[k]) + gzH[k]*gzH[k];
            acc += fabsf(outP - outH);
        }
    }

    // block reduction: wave64 shuffle, then across the 4 waves via LDS
    for (int o = 32; o > 0; o >>= 1) acc += __shfl_down(acc, o, 64);
    __shared__ float sred[BDIM / 64];
    const int lane = threadIdx.x & 63, wv = threadIdx.x >> 6;
    if (lane == 0) sred[wv] = acc;
    __syncthreads();
    if (threadIdx.x == 0) {
        float t = 0.f;
#pragma unroll
        for (int i = 0; i < BDIM / 64; ++i) t += sred[i];
        partial[(size_t)b * (F * F) + (size_t)z * F + y] = t;
    }
}

// ---------------- Finalize: sum 7200 partials in double, write mean ----------------
__global__ __launch_bounds__(BDIM) void finalize_kernel(
    const float* __restrict__ partial, float* __restrict__ out)
{
    double a = 0.0;
    for (int i = threadIdx.x; i < 2 * F * F; i += BDIM) a += (double)partial[i];
    for (int o = 32; o > 0; o >>= 1) a += __shfl_down(a, o, 64);
    __shared__ double sd[BDIM / 64];
    const int lane = threadIdx.x & 63, wv = threadIdx.x >> 6;
    if (lane == 0) sd[wv] = a;
    __syncthreads();
    if (threadIdx.x == 0) {
        double t = 0.0;
#pragma unroll
        for (int i = 0; i < BDIM / 64; ++i) t += sd[i];
        out[0] = (float)(t / 13824000.0);
    }
}

extern "C" void kernel_launch(void* const* d_in, const int* in_sizes, int n_in,
                              void* d_out, int out_size, void* d_ws, size_t ws_size,
                              hipStream_t stream)
{
    const float* pred = (const float*)d_in[0];
    const float* hr   = (const float*)d_in[1];

    // ws layout: [0, 28.8KB): 7200 float partials (fully overwritten each call)
    //            [64KB, ...): magP (fp16, 7.6M), magH (fp16, 7.6M)  ~29.2 MiB total
    float* partial = (float*)d_ws;
    __half* magP = (__half*)((char*)d_ws + 65536);
    __half* magH = magP + MAGSZ;

    for (int b = 0; b < 2; ++b) {
        sobel_mag_kernel<<<dim3(M, M, 2), BDIM, 0, stream>>>(pred, hr, magP, magH, b);
        sobel2_diff_kernel<<<dim3(F, F), BDIM, 0, stream>>>(magP, magH, partial, b);
    }
    finalize_kernel<<<1, BDIM, 0, stream>>>(partial, (float*)d_out);
}

// Round 3
// 357.232 us; speedup vs baseline: 1.4509x; 1.4509x over previous
//
#include <hip/hip_runtime.h>
#include <hip/hip_fp16.h>

// Problem geometry: inputs (B=2, D=64, H=64, W=64, C=32) fp32, C innermost.
// Pass1: Sobel (VALID) -> mag = sqrt(gx^2+gy^2+gz^2) at 62^3 per (b,c)
// Pass2: Sobel on mag -> out = sqrt(gx^2+gy^2) + gz^2 at 60^3
// Result: mean(|out_pred - out_hr|) over 2*32*60^3 = 13,824,000 elems.
//
// R3: separable per-thread y-blocking (SX/DX/SD row partials, 3-tap combine),
// float2/half2 loads, grid.x = y-tile / grid.y = z for XCD L2 z-plane reuse.
// Lesson from R2: keep VGPR <= ~90; occupancy is king here.

constexpr int BDIM = 256;
constexpr size_t IN_B = 8388608;   // 64*64*64*32 elements per batch
constexpr int IN_D = 131072;       // 64*64*32
constexpr int IN_H = 2048;         // 64*32
constexpr int M = 62;              // mag spatial dim
constexpr int F = 60;              // final spatial dim
constexpr int C = 32;
constexpr int MROW = M * C;                      // 1984
constexpr size_t MAGSZ = (size_t)M * M * MROW;   // halves per buffer
constexpr int YB1 = 4;             // pass1 y-outputs per thread
constexpr int YB2 = 2;             // pass2 y-outputs per thread

__device__ __forceinline__ float2 f2(float a, float b) { return make_float2(a, b); }

// ---------------- Pass 1: input -> fp16 magnitude volume ----------------
__global__ __launch_bounds__(BDIM) void sobel_mag_kernel(
    const float* __restrict__ pred, const float* __restrict__ hr,
    __half* __restrict__ magP, __half* __restrict__ magH, int b)
{
    const int z  = blockIdx.y;          // [0,62)
    const int y0 = blockIdx.x * YB1;    // 16 tiles cover 62 outputs
    const float* __restrict__ in  = blockIdx.z ? hr   : pred;
    __half*      __restrict__ mag = blockIdx.z ? magH : magP;
    const float* base = in + (size_t)b * IN_B + (size_t)z * IN_D + (size_t)y0 * IN_H;

    const int jmax = min(6, 64 - y0);       // input rows available (last tile: 4)
    const int kmax = min(YB1, M - y0);      // valid outputs (last tile: 2)

    for (int t = threadIdx.x; t < M * 16; t += BDIM) {
        const int x  = t >> 4;
        const int c2 = (t & 15) << 1;
        const float* p00 = base + x * C + c2;

        // Row partials: x-smooth/deriv pre-reduced over z-taps.
        float2 SX[6], DX[6], SD[6];
#pragma unroll
        for (int j = 0; j < 6; ++j) {
            if (j >= jmax) { SX[j] = f2(0,0); DX[j] = f2(0,0); SD[j] = f2(0,0); continue; }
            float2 sx[3], dx[3];
#pragma unroll
            for (int i = 0; i < 3; ++i) {
                const float* p = p00 + (size_t)i * IN_D + (size_t)j * IN_H;
                float2 v0 = *reinterpret_cast<const float2*>(p);
                float2 v1 = *reinterpret_cast<const float2*>(p + C);
                float2 v2 = *reinterpret_cast<const float2*>(p + 2 * C);
                sx[i] = f2(v0.x + 2.f * v1.x + v2.x, v0.y + 2.f * v1.y + v2.y);
                dx[i] = f2(v2.x - v0.x, v2.y - v0.y);
            }
            SX[j] = f2(sx[0].x + 2.f * sx[1].x + sx[2].x, sx[0].y + 2.f * sx[1].y + sx[2].y);
            DX[j] = f2(sx[2].x - sx[0].x, sx[2].y - sx[0].y);
            SD[j] = f2(dx[0].x + 2.f * dx[1].x + dx[2].x, dx[0].y + 2.f * dx[1].y + dx[2].y);
        }
        // 3-tap combine per output row k: gx=d_z, gy=d_y, gz=d_x
#pragma unroll
        for (int k = 0; k < YB1; ++k) {
            if (k >= kmax) break;
            float gxx = DX[k].x + 2.f * DX[k+1].x + DX[k+2].x;
            float gxy = DX[k].y + 2.f * DX[k+1].y + DX[k+2].y;
            float gyx = SX[k+2].x - SX[k].x;
            float gyy = SX[k+2].y - SX[k].y;
            float gzx = SD[k].x + 2.f * SD[k+1].x + SD[k+2].x;
            float gzy = SD[k].y + 2.f * SD[k+1].y + SD[k+2].y;
            float mx = sqrtf(gxx * gxx + gyx * gyx + gzx * gzx);
            float my = sqrtf(gxy * gxy + gyy * gyy + gzy * gzy);
            *reinterpret_cast<__half2*>(mag + ((size_t)z * M + (y0 + k)) * MROW + x * C + c2)
                = __floats2half2_rn(mx, my);
        }
    }
}

// ------- Pass 2: mag -> final, diff pred vs hr, per-block partial sum -------
__global__ __launch_bounds__(BDIM) void sobel2_diff_kernel(
    const __half* __restrict__ magP, const __half* __restrict__ magH,
    float* __restrict__ partial, int b)
{
    const int fz = blockIdx.y;         // [0,60)
    const int y0 = blockIdx.x * YB2;   // 30 tiles cover 60 exactly

    float acc = 0.f;
    for (int t = threadIdx.x; t < F * 16; t += BDIM) {
        const int x  = t >> 4;
        const int c2 = (t & 15) << 1;
        const size_t base = ((size_t)fz * M + y0) * MROW + x * C + c2;

        float2 SXP[4], DXP[4], SDP[4];
        float2 SXH[4], DXH[4], SDH[4];
#pragma unroll
        for (int j = 0; j < YB2 + 2; ++j) {
            float2 sxp[3], dxp[3], sxh[3], dxh[3];
#pragma unroll
            for (int i = 0; i < 3; ++i) {
                const size_t off = base + ((size_t)i * M + j) * MROW;
                float2 p0 = __half22float2(*reinterpret_cast<const __half2*>(magP + off));
                float2 p1 = __half22float2(*reinterpret_cast<const __half2*>(magP + off + C));
                float2 p2 = __half22float2(*reinterpret_cast<const __half2*>(magP + off + 2 * C));
                float2 h0 = __half22float2(*reinterpret_cast<const __half2*>(magH + off));
                float2 h1 = __half22float2(*reinterpret_cast<const __half2*>(magH + off + C));
                float2 h2 = __half22float2(*reinterpret_cast<const __half2*>(magH + off + 2 * C));
                sxp[i] = f2(p0.x + 2.f * p1.x + p2.x, p0.y + 2.f * p1.y + p2.y);
                dxp[i] = f2(p2.x - p0.x, p2.y - p0.y);
                sxh[i] = f2(h0.x + 2.f * h1.x + h2.x, h0.y + 2.f * h1.y + h2.y);
                dxh[i] = f2(h2.x - h0.x, h2.y - h0.y);
            }
            SXP[j] = f2(sxp[0].x + 2.f * sxp[1].x + sxp[2].x, sxp[0].y + 2.f * sxp[1].y + sxp[2].y);
            DXP[j] = f2(sxp[2].x - sxp[0].x, sxp[2].y - sxp[0].y);
            SDP[j] = f2(dxp[0].x + 2.f * dxp[1].x + dxp[2].x, dxp[0].y + 2.f * dxp[1].y + dxp[2].y);
            SXH[j] = f2(sxh[0].x + 2.f * sxh[1].x + sxh[2].x, sxh[0].y + 2.f * sxh[1].y + sxh[2].y);
            DXH[j] = f2(sxh[2].x - sxh[0].x, sxh[2].y - sxh[0].y);
            SDH[j] = f2(dxh[0].x + 2.f * dxh[1].x + dxh[2].x, dxh[0].y + 2.f * dxh[1].y + dxh[2].y);
        }
#pragma unroll
        for (int k = 0; k < YB2; ++k) {
            float gxPx = DXP[k].x + 2.f * DXP[k+1].x + DXP[k+2].x;
            float gxPy = DXP[k].y + 2.f * DXP[k+1].y + DXP[k+2].y;
            float gyPx = SXP[k+2].x - SXP[k].x;
            float gyPy = SXP[k+2].y - SXP[k].y;
            float gzPx = SDP[k].x + 2.f * SDP[k+1].x + SDP[k+2].x;
            float gzPy = SDP[k].y + 2.f * SDP[k+1].y + SDP[k+2].y;
            float gxHx = DXH[k].x + 2.f * DXH[k+1].x + DXH[k+2].x;
            float gxHy = DXH[k].y + 2.f * DXH[k+1].y + DXH[k+2].y;
            float gyHx = SXH[k+2].x - SXH[k].x;
            float gyHy = SXH[k+2].y - SXH[k].y;
            float gzHx = SDH[k].x + 2.f * SDH[k+1].x + SDH[k+2].x;
            float gzHy = SDH[k].y + 2.f * SDH[k+1].y + SDH[k+2].y;
            float oPx = sqrtf(gxPx * gxPx + gyPx * gyPx) + gzPx * gzPx;
            float oPy = sqrtf(gxPy * gxPy + gyPy * gyPy) + gzPy * gzPy;
            float oHx = sqrtf(gxHx * gxHx + gyHx * gyHx) + gzHx * gzHx;
            float oHy = sqrtf(gxHy * gxHy + gyHy * gyHy) + gzHy * gzHy;
            acc += fabsf(oPx - oHx) + fabsf(oPy - oHy);
        }
    }

    // block reduction: wave64 shuffle, then across the 4 waves via LDS
    for (int o = 32; o > 0; o >>= 1) acc += __shfl_down(acc, o, 64);
    __shared__ float sred[BDIM / 64];
    const int lane = threadIdx.x & 63, wv = threadIdx.x >> 6;
    if (lane == 0) sred[wv] = acc;
    __syncthreads();
    if (threadIdx.x == 0) {
        float ttl = 0.f;
#pragma unroll
        for (int i = 0; i < BDIM / 64; ++i) ttl += sred[i];
        partial[(size_t)b * 1800 + (size_t)blockIdx.y * 30 + blockIdx.x] = ttl;
    }
}

// ---------------- Finalize: sum 3600 partials in double, write mean ----------------
__global__ __launch_bounds__(BDIM) void finalize_kernel(
    const float* __restrict__ partial, float* __restrict__ out)
{
    double a = 0.0;
    for (int i = threadIdx.x; i < 3600; i += BDIM) a += (double)partial[i];
    for (int o = 32; o > 0; o >>= 1) a += __shfl_down(a, o, 64);
    __shared__ double sd[BDIM / 64];
    const int lane = threadIdx.x & 63, wv = threadIdx.x >> 6;
    if (lane == 0) sd[wv] = a;
    __syncthreads();
    if (threadIdx.x == 0) {
        double ttl = 0.0;
#pragma unroll
        for (int i = 0; i < BDIM / 64; ++i) ttl += sd[i];
        out[0] = (float)(ttl / 13824000.0);
    }
}

extern "C" void kernel_launch(void* const* d_in, const int* in_sizes, int n_in,
                              void* d_out, int out_size, void* d_ws, size_t ws_size,
                              hipStream_t stream)
{
    const float* pred = (const float*)d_in[0];
    const float* hr   = (const float*)d_in[1];

    // ws layout: [0, 14.4KB): 3600 float partials (fully overwritten each call)
    //            [64KB, ...): magP (fp16), magH (fp16)  ~29.2 MiB total
    float* partial = (float*)d_ws;
    __half* magP = (__half*)((char*)d_ws + 65536);
    __half* magH = magP + MAGSZ;

    for (int b = 0; b < 2; ++b) {
        sobel_mag_kernel<<<dim3(16, M, 2), BDIM, 0, stream>>>(pred, hr, magP, magH, b);
        sobel2_diff_kernel<<<dim3(30, F), BDIM, 0, stream>>>(magP, magH, partial, b);
    }
    finalize_kernel<<<1, BDIM, 0, stream>>>(partial, (float*)d_out);
}

// Round 4
// 245.516 us; speedup vs baseline: 2.1111x; 1.4550x over previous
//
#include <hip/hip_runtime.h>
#include <hip/hip_fp16.h>

// Problem geometry: inputs (B=2, D=64, H=64, W=64, C=32) fp32, C innermost.
// Pass1: Sobel (VALID) -> mag = sqrt(gx^2+gy^2+gz^2) at 62^3 per (b,c)
// Pass2: Sobel on mag -> out = sqrt(gx^2+gy^2) + gz^2 at 60^3
// Result: mean(|out_pred - out_hr|) over 2*32*60^3 = 13,824,000 elems.
//
// R4: register z-streaming. Each thread owns an (x, c2) column, walks z with a
// 3-plane rotating window of separable partials (A=y-smooth, B=y-deriv,
// C=x-deriv-y-smooth). 18 (p1) / 24 (p2) independent loads per step -> high
// MLP per wave; z-reuse in registers. R3 lesson: kernel was latency-bound
// (all pipes <30%); R2 lesson: avoid indexed arrays -> explicit 3-way rotation.

constexpr int BDIM = 256;
constexpr size_t IN_B = 8388608;   // 64*64*64*32 elements per batch
constexpr int IN_D = 131072;       // 64*64*32
constexpr int IN_H = 2048;         // 64*32
constexpr int M = 62;              // mag spatial dim
constexpr int F = 60;              // final spatial dim
constexpr int C = 32;
constexpr int MROW = M * C;                      // 1984
constexpr size_t MAGSZ = (size_t)M * M * MROW;   // halves per buffer
constexpr size_t PLANE = (size_t)M * MROW;       // halves per mag z-plane

__device__ __forceinline__ float2 ld2(const float* p) {
    return *reinterpret_cast<const float2*>(p);
}
__device__ __forceinline__ float2 ldh2(const __half* p) {
    return __half22float2(*reinterpret_cast<const __half2*>(p));
}

// ================= Pass 1: input -> fp16 magnitude, z-streamed =================
struct P1W { float2 A[4], B[4], C[4]; };   // per-plane partials for 4 output rows

__device__ __forceinline__ void p1_plane(const float* __restrict__ col, size_t zoff,
                                         const int jr[6], P1W& W)
{
    float2 SX[6], DX[6];
#pragma unroll
    for (int j = 0; j < 6; ++j) {
        const float* p = col + zoff + jr[j];
        float2 a = ld2(p), b = ld2(p + C), c = ld2(p + 2 * C);
        SX[j] = make_float2(a.x + 2.f * b.x + c.x, a.y + 2.f * b.y + c.y);
        DX[j] = make_float2(c.x - a.x, c.y - a.y);
    }
#pragma unroll
    for (int k = 0; k < 4; ++k) {
        W.A[k] = make_float2(SX[k].x + 2.f * SX[k+1].x + SX[k+2].x,
                             SX[k].y + 2.f * SX[k+1].y + SX[k+2].y);
        W.B[k] = make_float2(SX[k+2].x - SX[k].x, SX[k+2].y - SX[k].y);
        W.C[k] = make_float2(DX[k].x + 2.f * DX[k+1].x + DX[k+2].x,
                             DX[k].y + 2.f * DX[k+1].y + DX[k+2].y);
    }
}

__device__ __forceinline__ void p1_emit(const P1W& W0, const P1W& W1, const P1W& W2,
                                        __half* __restrict__ mag, size_t cb,
                                        int z, int y0, int kmax, bool xok)
{
    if (!xok) return;
#pragma unroll
    for (int k = 0; k < 4; ++k) {
        if (k < kmax) {
            float gxx = W2.A[k].x - W0.A[k].x;
            float gxy = W2.A[k].y - W0.A[k].y;
            float gyx = W0.B[k].x + 2.f * W1.B[k].x + W2.B[k].x;
            float gyy = W0.B[k].y + 2.f * W1.B[k].y + W2.B[k].y;
            float gzx = W0.C[k].x + 2.f * W1.C[k].x + W2.C[k].x;
            float gzy = W0.C[k].y + 2.f * W1.C[k].y + W2.C[k].y;
            float mx = sqrtf(gxx * gxx + gyx * gyx + gzx * gzx);
            float my = sqrtf(gxy * gxy + gyy * gyy + gzy * gzy);
            *reinterpret_cast<__half2*>(mag + ((size_t)z * M + (y0 + k)) * MROW + cb)
                = __floats2half2_rn(mx, my);
        }
    }
}

__global__ __launch_bounds__(BDIM) void sobel_mag_stream(
    const float* __restrict__ pred, const float* __restrict__ hr,
    __half* __restrict__ magP, __half* __restrict__ magH, int b)
{
    const int xt = blockIdx.x & 3, yt = blockIdx.x >> 2;   // grid.x = 64
    const int zc = blockIdx.y;                             // [0,8)
    const float* __restrict__ in  = blockIdx.z ? hr   : pred;
    __half*      __restrict__ mag = blockIdx.z ? magH : magP;

    const int y0 = yt * 4;
    const int z0 = zc * 8;
    const int zn = min(8, M - z0);        // 8 or 6
    const int kmax = min(4, M - y0);      // 4 or (last tile) 2
    const int xraw = xt * 16 + (threadIdx.x >> 4);
    const bool xok = xraw < M;
    const int x = min(xraw, M - 1);
    const int c2 = (threadIdx.x & 15) << 1;

    int jr[6];
#pragma unroll
    for (int j = 0; j < 6; ++j) jr[j] = min(y0 + j, 63) * IN_H;

    const float* col = in + (size_t)b * IN_B + (size_t)x * C + c2;
    const size_t cb = (size_t)x * C + c2;

    P1W W0, W1, W2;
    p1_plane(col, (size_t)(z0 + 0) * IN_D, jr, W0);
    p1_plane(col, (size_t)(z0 + 1) * IN_D, jr, W1);
    int z = 0;
    while (true) {
        p1_plane(col, (size_t)(z0 + z + 2) * IN_D, jr, W2);
        p1_emit(W0, W1, W2, mag, cb, z0 + z, y0, kmax, xok);
        if (++z >= zn) break;
        p1_plane(col, (size_t)(z0 + z + 2) * IN_D, jr, W0);
        p1_emit(W1, W2, W0, mag, cb, z0 + z, y0, kmax, xok);
        if (++z >= zn) break;
        p1_plane(col, (size_t)(z0 + z + 2) * IN_D, jr, W1);
        p1_emit(W2, W0, W1, mag, cb, z0 + z, y0, kmax, xok);
        if (++z >= zn) break;
    }
}

// ============ Pass 2: mag -> final, diff, partial sums, z-streamed ============
struct P2W { float2 A[2], B[2], C[2]; };

__device__ __forceinline__ void p2_plane(const __half* __restrict__ col, size_t zoff, P2W& W)
{
    float2 SX[4], DX[4];
#pragma unroll
    for (int j = 0; j < 4; ++j) {
        const __half* p = col + zoff + (size_t)j * MROW;
        float2 a = ldh2(p), b = ldh2(p + C), c = ldh2(p + 2 * C);
        SX[j] = make_float2(a.x + 2.f * b.x + c.x, a.y + 2.f * b.y + c.y);
        DX[j] = make_float2(c.x - a.x, c.y - a.y);
    }
#pragma unroll
    for (int k = 0; k < 2; ++k) {
        W.A[k] = make_float2(SX[k].x + 2.f * SX[k+1].x + SX[k+2].x,
                             SX[k].y + 2.f * SX[k+1].y + SX[k+2].y);
        W.B[k] = make_float2(SX[k+2].x - SX[k].x, SX[k+2].y - SX[k].y);
        W.C[k] = make_float2(DX[k].x + 2.f * DX[k+1].x + DX[k+2].x,
                             DX[k].y + 2.f * DX[k+1].y + DX[k+2].y);
    }
}

__device__ __forceinline__ void p2_emit(const P2W& P0, const P2W& P1, const P2W& P2,
                                        const P2W& H0, const P2W& H1, const P2W& H2,
                                        float& acc)
{
#pragma unroll
    for (int k = 0; k < 2; ++k) {
        float gxPx = P2.A[k].x - P0.A[k].x;
        float gxPy = P2.A[k].y - P0.A[k].y;
        float gyPx = P0.B[k].x + 2.f * P1.B[k].x + P2.B[k].x;
        float gyPy = P0.B[k].y + 2.f * P1.B[k].y + P2.B[k].y;
        float gzPx = P0.C[k].x + 2.f * P1.C[k].x + P2.C[k].x;
        float gzPy = P0.C[k].y + 2.f * P1.C[k].y + P2.C[k].y;
        float gxHx = H2.A[k].x - H0.A[k].x;
        float gxHy = H2.A[k].y - H0.A[k].y;
        float gyHx = H0.B[k].x + 2.f * H1.B[k].x + H2.B[k].x;
        float gyHy = H0.B[k].y + 2.f * H1.B[k].y + H2.B[k].y;
        float gzHx = H0.C[k].x + 2.f * H1.C[k].x + H2.C[k].x;
        float gzHy = H0.C[k].y + 2.f * H1.C[k].y + H2.C[k].y;
        float oPx = sqrtf(gxPx * gxPx + gyPx * gyPx) + gzPx * gzPx;
        float oPy = sqrtf(gxPy * gxPy + gyPy * gyPy) + gzPy * gzPy;
        float oHx = sqrtf(gxHx * gxHx + gyHx * gyHx) + gzHx * gzHx;
        float oHy = sqrtf(gxHy * gxHy + gyHy * gyHy) + gzHy * gzHy;
        acc += fabsf(oPx - oHx) + fabsf(oPy - oHy);
    }
}

__global__ __launch_bounds__(BDIM) void sobel2_stream(
    const __half* __restrict__ magP, const __half* __restrict__ magH,
    float* __restrict__ partial, int b)
{
    const int xt = blockIdx.x & 3, yt = blockIdx.x >> 2;   // grid.x = 120
    const int zc = blockIdx.y;                             // [0,6)
    const int y0 = yt * 2;
    const int z0 = zc * 10;
    const int xraw = xt * 16 + (threadIdx.x >> 4);
    const bool xok = xraw < F;
    const int x = min(xraw, F - 1);
    const int c2 = (threadIdx.x & 15) << 1;

    const size_t colo = (size_t)y0 * MROW + (size_t)x * C + c2;
    const __half* colP = magP + colo;
    const __half* colH = magH + colo;

    P2W P0, P1, P2, H0, H1, H2;
    p2_plane(colP, (size_t)(z0 + 0) * PLANE, P0);
    p2_plane(colH, (size_t)(z0 + 0) * PLANE, H0);
    p2_plane(colP, (size_t)(z0 + 1) * PLANE, P1);
    p2_plane(colH, (size_t)(z0 + 1) * PLANE, H1);
    float acc = 0.f;
    int z = 0;
    while (true) {
        p2_plane(colP, (size_t)(z0 + z + 2) * PLANE, P2);
        p2_plane(colH, (size_t)(z0 + z + 2) * PLANE, H2);
        if (xok) p2_emit(P0, P1, P2, H0, H1, H2, acc);
        if (++z >= 10) break;
        p2_plane(colP, (size_t)(z0 + z + 2) * PLANE, P0);
        p2_plane(colH, (size_t)(z0 + z + 2) * PLANE, H0);
        if (xok) p2_emit(P1, P2, P0, H1, H2, H0, acc);
        if (++z >= 10) break;
        p2_plane(colP, (size_t)(z0 + z + 2) * PLANE, P1);
        p2_plane(colH, (size_t)(z0 + z + 2) * PLANE, H1);
        if (xok) p2_emit(P2, P0, P1, H2, H0, H1, acc);
        if (++z >= 10) break;
    }

    // block reduction: wave64 shuffle, then across the 4 waves via LDS
    for (int o = 32; o > 0; o >>= 1) acc += __shfl_down(acc, o, 64);
    __shared__ float sred[BDIM / 64];
    const int lane = threadIdx.x & 63, wv = threadIdx.x >> 6;
    if (lane == 0) sred[wv] = acc;
    __syncthreads();
    if (threadIdx.x == 0) {
        float t = 0.f;
#pragma unroll
        for (int i = 0; i < BDIM / 64; ++i) t += sred[i];
        partial[(size_t)b * 720 + (size_t)zc * 120 + blockIdx.x] = t;
    }
}

// -------- Finalize: sum 1440 partials in double, write mean --------
__global__ __launch_bounds__(BDIM) void finalize_kernel(
    const float* __restrict__ partial, float* __restrict__ out)
{
    double a = 0.0;
    for (int i = threadIdx.x; i < 1440; i += BDIM) a += (double)partial[i];
    for (int o = 32; o > 0; o >>= 1) a += __shfl_down(a, o, 64);
    __shared__ double sd[BDIM / 64];
    const int lane = threadIdx.x & 63, wv = threadIdx.x >> 6;
    if (lane == 0) sd[wv] = a;
    __syncthreads();
    if (threadIdx.x == 0) {
        double t = 0.0;
#pragma unroll
        for (int i = 0; i < BDIM / 64; ++i) t += sd[i];
        out[0] = (float)(t / 13824000.0);
    }
}

extern "C" void kernel_launch(void* const* d_in, const int* in_sizes, int n_in,
                              void* d_out, int out_size, void* d_ws, size_t ws_size,
                              hipStream_t stream)
{
    const float* pred = (const float*)d_in[0];
    const float* hr   = (const float*)d_in[1];

    // ws layout: [0, 5.76KB): 1440 float partials (fully overwritten each call)
    //            [64KB, ...): magP (fp16), magH (fp16)  ~29.2 MiB total
    float* partial = (float*)d_ws;
    __half* magP = (__half*)((char*)d_ws + 65536);
    __half* magH = magP + MAGSZ;

    for (int b = 0; b < 2; ++b) {
        sobel_mag_stream<<<dim3(64, 8, 2), BDIM, 0, stream>>>(pred, hr, magP, magH, b);
        sobel2_stream<<<dim3(120, 6), BDIM, 0, stream>>>(magP, magH, partial, b);
    }
    finalize_kernel<<<1, BDIM, 0, stream>>>(partial, (float*)d_out);
}